// Round 2
// baseline (2364.483 us; speedup 1.0000x reference)
//
#include <hip/hip_runtime.h>

#define NEG_SLOPE 0.2f

// ---------------- K1: per-edge attr segment-sum + in-degree count ----------------
__global__ void k_edge_accum(const int* __restrict__ dst, const float* __restrict__ edge_attr,
                             float* __restrict__ attr_sum, float* __restrict__ cnt, int E) {
    int e = blockIdx.x * blockDim.x + threadIdx.x;
    if (e >= E) return;
    int d = dst[e];
    const float* ap = edge_attr + (size_t)e * 11;
    float* as = attr_sum + (size_t)d * 11;
#pragma unroll
    for (int k = 0; k < 11; ++k) atomicAdd(&as[k], ap[k]);
    atomicAdd(&cnt[d], 1.0f);
}

// ---------------- K2: fused node encoder + xl/xr transforms ----------------
// block = 256 threads, handles 16 nodes; thread j owns output column j (0..255)
__global__ void __launch_bounds__(256) k_enc_xlxr(
    const float* __restrict__ x, const int* __restrict__ node_type,
    const float* __restrict__ type_emb,
    const float* __restrict__ enc_W, const float* __restrict__ enc_b,
    const float* __restrict__ Wl, const float* __restrict__ bl,
    const float* __restrict__ Wr, const float* __restrict__ br,
    float* __restrict__ xl, float* __restrict__ xr, int N) {
    const int NPB = 16;
    __shared__ float sIn[NPB][10];
    __shared__ float sH[NPB][64];
    int tid = threadIdx.x;
    int v0 = blockIdx.x * NPB;
    for (int i = tid; i < NPB * 10; i += 256) {
        int v = i / 10, k = i % 10;
        int vg = v0 + v;
        float val = 0.f;
        if (vg < N) {
            if (k < 6) val = x[(size_t)vg * 6 + k];
            else       val = type_emb[node_type[vg] * 4 + (k - 6)];
        }
        sIn[v][k] = val;
    }
    __syncthreads();
    for (int i = tid; i < NPB * 64; i += 256) {
        int v = i >> 6, j = i & 63;
        float acc = enc_b[j];
#pragma unroll
        for (int k = 0; k < 10; ++k) acc += sIn[v][k] * enc_W[k * 64 + j];
        sH[v][j] = fmaxf(acc, 0.f);
    }
    __syncthreads();
    int j = tid;  // 0..255
    float accL[NPB], accR[NPB];
    float blj = bl[j], brj = br[j];
#pragma unroll
    for (int v = 0; v < NPB; ++v) { accL[v] = blj; accR[v] = brj; }
    for (int k = 0; k < 64; ++k) {
        float wl = Wl[k * 256 + j], wr = Wr[k * 256 + j];
#pragma unroll
        for (int v = 0; v < NPB; ++v) {
            float hv = sH[v][k];
            accL[v] += hv * wl;
            accR[v] += hv * wr;
        }
    }
#pragma unroll
    for (int v = 0; v < NPB; ++v) {
        int vg = v0 + v;
        if (vg < N) {
            xl[(size_t)vg * 256 + j] = accL[v];
            xr[(size_t)vg * 256 + j] = accR[v];
        }
    }
}

// ---------------- K3: finalize self-loop attrs ----------------
__global__ void k_loop_attr(const float* __restrict__ attr_sum, const float* __restrict__ cnt,
                            float* __restrict__ loop_attr, int N) {
    int v = blockIdx.x * blockDim.x + threadIdx.x;
    if (v >= N) return;
    float inv = 1.0f / fmaxf(cnt[v], 1.0f);
#pragma unroll
    for (int k = 0; k < 11; ++k) loop_attr[(size_t)v * 11 + k] = attr_sum[(size_t)v * 11 + k] * inv;
}

// ---------------- K4: per-edge logits + softmax denom (one wave per edge) ----------------
__global__ void __launch_bounds__(256) k_edge_logits(
    const int* __restrict__ src, const int* __restrict__ dst,
    const float* __restrict__ edge_attr, const float* __restrict__ loop_attr,
    const float* __restrict__ We, const float* __restrict__ att,
    const float* __restrict__ xl, const float* __restrict__ xr,
    float* __restrict__ logits, float* __restrict__ denom, int E, int N) {
    __shared__ float sWe[11 * 256];
    int tid = threadIdx.x;
    for (int i = tid; i < 11 * 256; i += 256) sWe[i] = We[i];
    __syncthreads();
    int lane = tid & 63;
    int e = blockIdx.x * 4 + (tid >> 6);
    if (e >= E + N) return;
    int s, d; const float* ap;
    if (e < E) { s = src[e]; d = dst[e]; ap = edge_attr + (size_t)e * 11; }
    else       { s = d = e - E;          ap = loop_attr + (size_t)(e - E) * 11; }
    float a[11];
#pragma unroll
    for (int k = 0; k < 11; ++k) a[k] = ap[k];
    const float* xls = xl + (size_t)s * 256;
    const float* xrd = xr + (size_t)d * 256;
    float red[4];
#pragma unroll
    for (int h = 0; h < 4; ++h) {
        int col = h * 64 + lane;
        float ee = 0.f;
#pragma unroll
        for (int k = 0; k < 11; ++k) ee += a[k] * sWe[k * 256 + col];
        float m = xls[col] + xrd[col] + ee;
        m = (m > 0.f) ? m : NEG_SLOPE * m;
        float acc = m * att[col];
#pragma unroll
        for (int off = 32; off > 0; off >>= 1) acc += __shfl_xor(acc, off, 64);
        red[h] = acc;
    }
    if (lane == 0) {
#pragma unroll
        for (int h = 0; h < 4; ++h) {
            logits[(size_t)e * 4 + h] = red[h];
            atomicAdd(&denom[(size_t)d * 4 + h], expf(red[h]));
        }
    }
}

// ---------------- K5: weighted scatter into out_feat (one wave per edge) ----------------
__global__ void __launch_bounds__(256) k_edge_scatter(
    const int* __restrict__ src, const int* __restrict__ dst,
    const float* __restrict__ logits, const float* __restrict__ denom,
    const float* __restrict__ xl, float* __restrict__ out_feat, int E, int N) {
    int tid = threadIdx.x;
    int lane = tid & 63;
    int e = blockIdx.x * 4 + (tid >> 6);
    if (e >= E + N) return;
    int s, d;
    if (e < E) { s = src[e]; d = dst[e]; }
    else       { s = d = e - E; }
    const float* xls = xl + (size_t)s * 256;
    float* ofd = out_feat + (size_t)d * 256;
#pragma unroll
    for (int h = 0; h < 4; ++h) {
        float w = expf(logits[(size_t)e * 4 + h]) / (denom[(size_t)d * 4 + h] + 1e-16f);
        int col = h * 64 + lane;
        atomicAdd(&ofd[col], w * xls[col]);
    }
}

// ---------------- K6: head-mean + relu + graph pooling ----------------
__global__ void k_node_pool(const float* __restrict__ out_feat, const float* __restrict__ conv_bias,
                            const int* __restrict__ batch, float* __restrict__ pooled,
                            float* __restrict__ gcnt, int N) {
    int idx = blockIdx.x * blockDim.x + threadIdx.x;
    if (idx >= N * 64) return;
    int v = idx >> 6, c = idx & 63;
    const float* of = out_feat + (size_t)v * 256;
    float s = 0.25f * (of[c] + of[64 + c] + of[128 + c] + of[192 + c]);
    float hc = fmaxf(s + conv_bias[c], 0.f);
    int g = batch[v];
    atomicAdd(&pooled[g * 64 + c], hc);
    if (c == 0) atomicAdd(&gcnt[g], 1.0f);
}

// ---------------- K7: per-graph MLP head ----------------
__global__ void k_final(const float* __restrict__ pooled, const float* __restrict__ gcnt,
                        const float* __restrict__ gf, const float* __restrict__ gW,
                        const float* __restrict__ gb, const float* __restrict__ h1W,
                        const float* __restrict__ h1b, const float* __restrict__ h2W,
                        const float* __restrict__ h2b, float* __restrict__ out, int G) {
    __shared__ float sComb[128];
    __shared__ float sHid[64];
    int g = blockIdx.x;
    int t = threadIdx.x;
    if (t < 64) {
        sComb[t] = pooled[(size_t)g * 64 + t] / fmaxf(gcnt[g], 1.0f);
    } else {
        int j = t - 64;
        float acc = gb[j];
#pragma unroll
        for (int k = 0; k < 6; ++k) acc += gf[(size_t)g * 6 + k] * gW[k * 64 + j];
        sComb[64 + j] = fmaxf(acc, 0.f);
    }
    __syncthreads();
    if (t < 64) {
        float acc = h1b[t];
#pragma unroll
        for (int k = 0; k < 128; ++k) acc += sComb[k] * h1W[k * 64 + t];
        sHid[t] = fmaxf(acc, 0.f);
    }
    __syncthreads();
    if (t < 64) {
        float p = sHid[t] * h2W[t];
#pragma unroll
        for (int off = 32; off > 0; off >>= 1) p += __shfl_xor(p, off, 64);
        if (t == 0) out[g] = p + h2b[0];
    }
}

extern "C" void kernel_launch(void* const* d_in, const int* in_sizes, int n_in,
                              void* d_out, int out_size, void* d_ws, size_t ws_size,
                              hipStream_t stream) {
    const float* x         = (const float*)d_in[0];
    const int*   node_type = (const int*)d_in[1];
    const int*   edge_index= (const int*)d_in[2];
    const float* edge_attr = (const float*)d_in[3];
    const int*   batch     = (const int*)d_in[4];
    const float* gf        = (const float*)d_in[5];
    const float* type_emb  = (const float*)d_in[6];
    const float* enc_W     = (const float*)d_in[7];
    const float* enc_b     = (const float*)d_in[8];
    const float* Wl        = (const float*)d_in[9];
    const float* bl        = (const float*)d_in[10];
    const float* Wr        = (const float*)d_in[11];
    const float* br        = (const float*)d_in[12];
    const float* We        = (const float*)d_in[13];
    const float* att       = (const float*)d_in[14];
    const float* conv_bias = (const float*)d_in[15];
    const float* gW        = (const float*)d_in[16];
    const float* gb        = (const float*)d_in[17];
    const float* h1W       = (const float*)d_in[18];
    const float* h1b       = (const float*)d_in[19];
    const float* h2W       = (const float*)d_in[20];
    const float* h2b       = (const float*)d_in[21];
    float* out = (float*)d_out;

    const int N = in_sizes[0] / 6;
    const int E = in_sizes[2] / 2;
    const int G = in_sizes[5] / 6;

    const int* srcArr = edge_index;
    const int* dstArr = edge_index + E;

    // workspace layout (floats). out_feat overlays xr (dead after K4).
    float* ws = (float*)d_ws;
    size_t off = 0;
    float* xl       = ws + off; off += (size_t)N * 256;
    float* xr       = ws + off; off += (size_t)N * 256;
    float* out_feat = xr;  // overlay: xr dead after K4
    float* logits   = ws + off; off += (size_t)(E + N) * 4;
    size_t zs = off;
    float* attr_sum = ws + off; off += (size_t)N * 11;
    float* cnt      = ws + off; off += (size_t)N;
    float* denom    = ws + off; off += (size_t)N * 4;
    float* pooled   = ws + off; off += (size_t)G * 64;
    float* gcnt     = ws + off; off += (size_t)G;
    size_t ze = off;
    float* loop_attr= ws + off; off += (size_t)N * 11;
    (void)ws_size; (void)n_in; (void)out_size;

    hipMemsetAsync(ws + zs, 0, (ze - zs) * sizeof(float), stream);

    k_edge_accum<<<(E + 255) / 256, 256, 0, stream>>>(dstArr, edge_attr, attr_sum, cnt, E);
    k_enc_xlxr<<<(N + 15) / 16, 256, 0, stream>>>(x, node_type, type_emb, enc_W, enc_b,
                                                  Wl, bl, Wr, br, xl, xr, N);
    k_loop_attr<<<(N + 255) / 256, 256, 0, stream>>>(attr_sum, cnt, loop_attr, N);

    int ET = E + N;
    k_edge_logits<<<(ET + 3) / 4, 256, 0, stream>>>(srcArr, dstArr, edge_attr, loop_attr,
                                                    We, att, xl, xr, logits, denom, E, N);
    // zero out_feat (overlaid on xr) now that K4 consumed xr
    hipMemsetAsync(out_feat, 0, (size_t)N * 256 * sizeof(float), stream);
    k_edge_scatter<<<(ET + 3) / 4, 256, 0, stream>>>(srcArr, dstArr, logits, denom,
                                                     xl, out_feat, E, N);
    k_node_pool<<<((size_t)N * 64 + 255) / 256, 256, 0, stream>>>(out_feat, conv_bias, batch,
                                                                  pooled, gcnt, N);
    k_final<<<G, 128, 0, stream>>>(pooled, gcnt, gf, gW, gb, h1W, h1b, h2W, h2b, out, G);
}

// Round 3
// 1414.767 us; speedup vs baseline: 1.6713x; 1.6713x over previous
//
#include <hip/hip_runtime.h>

#define NEG_SLOPE 0.2f

// ---------------- K1: per-edge degree histogram + attr segment-sum ----------------
__global__ void k_hist_accum(const int* __restrict__ dst, const float* __restrict__ edge_attr,
                             float* __restrict__ attr_sum, int* __restrict__ degi, int E) {
    int e = blockIdx.x * blockDim.x + threadIdx.x;
    if (e >= E) return;
    int d = dst[e];
    const float* ap = edge_attr + (size_t)e * 11;
    float* as = attr_sum + (size_t)d * 11;
#pragma unroll
    for (int k = 0; k < 11; ++k) atomicAdd(&as[k], ap[k]);
    atomicAdd(&degi[d], 1);
}

// ---------------- K2: single-block exclusive scan of degrees -> row_ptr ----------------
__global__ void __launch_bounds__(1024) k_scan(const int* __restrict__ degi,
                                               int* __restrict__ row_ptr, int N) {
    __shared__ int wsum[16];
    __shared__ int srun;
    int tid = threadIdx.x, lane = tid & 63, wid = tid >> 6;
    if (tid == 0) srun = 0;
    __syncthreads();
    for (int base = 0; base < N; base += 1024) {
        int i = base + tid;
        int v = (i < N) ? degi[i] : 0;
        int x = v;
#pragma unroll
        for (int off = 1; off < 64; off <<= 1) {
            int y = __shfl_up(x, off, 64);
            if (lane >= off) x += y;
        }
        if (lane == 63) wsum[wid] = x;
        __syncthreads();
        if (wid == 0) {
            int w = (lane < 16) ? wsum[lane] : 0;
#pragma unroll
            for (int off = 1; off < 16; off <<= 1) {
                int y = __shfl_up(w, off, 64);
                if (lane >= off) w += y;
            }
            if (lane < 16) wsum[lane] = w;  // inclusive wave sums
        }
        __syncthreads();
        int wofs = (wid > 0) ? wsum[wid - 1] : 0;
        int run = srun;
        if (i < N) row_ptr[i] = run + wofs + x - v;  // exclusive
        __syncthreads();
        if (tid == 1023) srun = run + wsum[15];
        __syncthreads();
    }
    if (tid == 0) row_ptr[N] = srun;
}

// ---------------- K3: CSR fill (edge ids bucketed by dst) ----------------
__global__ void k_fill(const int* __restrict__ dst, const int* __restrict__ row_ptr,
                       int* __restrict__ cursor, int* __restrict__ eidx, int E) {
    int e = blockIdx.x * blockDim.x + threadIdx.x;
    if (e >= E) return;
    int d = dst[e];
    int pos = atomicAdd(&cursor[d], 1);
    eidx[row_ptr[d] + pos] = e;
}

// ---------------- K4: finalize self-loop attrs ----------------
__global__ void k_loop_attr(const float* __restrict__ attr_sum, const int* __restrict__ degi,
                            float* __restrict__ loop_attr, int N) {
    int v = blockIdx.x * blockDim.x + threadIdx.x;
    if (v >= N) return;
    float inv = 1.0f / fmaxf((float)degi[v], 1.0f);
#pragma unroll
    for (int k = 0; k < 11; ++k) loop_attr[(size_t)v * 11 + k] = attr_sum[(size_t)v * 11 + k] * inv;
}

// ---------------- K5: fused node encoder + xl/xr transforms ----------------
__global__ void __launch_bounds__(256) k_enc_xlxr(
    const float* __restrict__ x, const int* __restrict__ node_type,
    const float* __restrict__ type_emb,
    const float* __restrict__ enc_W, const float* __restrict__ enc_b,
    const float* __restrict__ Wl, const float* __restrict__ bl,
    const float* __restrict__ Wr, const float* __restrict__ br,
    float* __restrict__ xl, float* __restrict__ xr, int N) {
    const int NPB = 16;
    __shared__ float sIn[NPB][10];
    __shared__ float sH[NPB][64];
    int tid = threadIdx.x;
    int v0 = blockIdx.x * NPB;
    for (int i = tid; i < NPB * 10; i += 256) {
        int v = i / 10, k = i % 10;
        int vg = v0 + v;
        float val = 0.f;
        if (vg < N) {
            if (k < 6) val = x[(size_t)vg * 6 + k];
            else       val = type_emb[node_type[vg] * 4 + (k - 6)];
        }
        sIn[v][k] = val;
    }
    __syncthreads();
    for (int i = tid; i < NPB * 64; i += 256) {
        int v = i >> 6, j = i & 63;
        float acc = enc_b[j];
#pragma unroll
        for (int k = 0; k < 10; ++k) acc += sIn[v][k] * enc_W[k * 64 + j];
        sH[v][j] = fmaxf(acc, 0.f);
    }
    __syncthreads();
    int j = tid;
    float accL[NPB], accR[NPB];
    float blj = bl[j], brj = br[j];
#pragma unroll
    for (int v = 0; v < NPB; ++v) { accL[v] = blj; accR[v] = brj; }
    for (int k = 0; k < 64; ++k) {
        float wl = Wl[k * 256 + j], wr = Wr[k * 256 + j];
#pragma unroll
        for (int v = 0; v < NPB; ++v) {
            float hv = sH[v][k];
            accL[v] += hv * wl;
            accR[v] += hv * wr;
        }
    }
#pragma unroll
    for (int v = 0; v < NPB; ++v) {
        int vg = v0 + v;
        if (vg < N) {
            xl[(size_t)vg * 256 + j] = accL[v];
            xr[(size_t)vg * 256 + j] = accR[v];
        }
    }
}

// ---------------- K6: fused per-node GATv2 (logits + softmax + aggregate + mean + relu + pool) ----------------
// one wave per node; lane l owns cols {l, 64+l, 128+l, 192+l} (one per head)
__global__ void __launch_bounds__(256) k_gather(
    const int* __restrict__ src, const float* __restrict__ edge_attr,
    const float* __restrict__ loop_attr, const int* __restrict__ row_ptr,
    const int* __restrict__ eidx, const float* __restrict__ We,
    const float* __restrict__ att, const float* __restrict__ xl,
    const float* __restrict__ xr, const float* __restrict__ conv_bias,
    const int* __restrict__ batch, float* __restrict__ pooled,
    float* __restrict__ gcnt, int N) {
    __shared__ float sWe[11 * 256];
    int tid = threadIdx.x;
    for (int i = tid; i < 11 * 256; i += 256) sWe[i] = We[i];
    __syncthreads();
    int lane = tid & 63;
    int v = blockIdx.x * 4 + (tid >> 6);
    if (v >= N) return;

    float attv[4], xrv[4], acc[4], den[4];
#pragma unroll
    for (int h = 0; h < 4; ++h) {
        int col = h * 64 + lane;
        attv[h] = att[col];
        xrv[h] = xr[(size_t)v * 256 + col];
        acc[h] = 0.f;
        den[h] = 0.f;
    }
    int rs = row_ptr[v], re = row_ptr[v + 1];

    // chunked edge loop + final self-loop iteration
    for (int base = rs; base <= re; base += 64) {
        int cnt = re - base;
        if (cnt > 64) cnt = 64;
        int idx = base + lane;
        int myE = (lane < cnt) ? eidx[idx] : 0;
        int myS = (lane < cnt) ? src[myE] : 0;
        int iters = cnt;
        bool doLoop = (base + 64 > re);  // last chunk also handles self-loop
        for (int t = 0; t < iters + (doLoop ? 1 : 0); ++t) {
            int s; const float* ap;
            if (t < iters) {
                int e = __shfl(myE, t, 64);
                s = __shfl(myS, t, 64);
                ap = edge_attr + (size_t)e * 11;
            } else {
                s = v;
                ap = loop_attr + (size_t)v * 11;
            }
            float a[11];
#pragma unroll
            for (int k = 0; k < 11; ++k) a[k] = ap[k];
            const float* xls = xl + (size_t)s * 256;
#pragma unroll
            for (int h = 0; h < 4; ++h) {
                int col = h * 64 + lane;
                float xlv = xls[col];
                float ee = 0.f;
#pragma unroll
                for (int k = 0; k < 11; ++k) ee += a[k] * sWe[k * 256 + col];
                float m = xlv + xrv[h] + ee;
                m = (m > 0.f) ? m : NEG_SLOPE * m;
                float t2 = m * attv[h];
#pragma unroll
                for (int off = 32; off > 0; off >>= 1) t2 += __shfl_xor(t2, off, 64);
                float p = expf(t2);
                acc[h] += p * xlv;
                den[h] += p;
            }
        }
    }

    float s4 = 0.f;
#pragma unroll
    for (int h = 0; h < 4; ++h) s4 += acc[h] / (den[h] + 1e-16f);
    float hc = fmaxf(0.25f * s4 + conv_bias[lane], 0.f);
    int g = batch[v];
    atomicAdd(&pooled[g * 64 + lane], hc);
    if (lane == 0) atomicAdd(&gcnt[g], 1.0f);
}

// ---------------- K7: per-graph MLP head ----------------
__global__ void k_final(const float* __restrict__ pooled, const float* __restrict__ gcnt,
                        const float* __restrict__ gf, const float* __restrict__ gW,
                        const float* __restrict__ gb, const float* __restrict__ h1W,
                        const float* __restrict__ h1b, const float* __restrict__ h2W,
                        const float* __restrict__ h2b, float* __restrict__ out, int G) {
    __shared__ float sComb[128];
    __shared__ float sHid[64];
    int g = blockIdx.x;
    int t = threadIdx.x;
    if (t < 64) {
        sComb[t] = pooled[(size_t)g * 64 + t] / fmaxf(gcnt[g], 1.0f);
    } else {
        int j = t - 64;
        float acc = gb[j];
#pragma unroll
        for (int k = 0; k < 6; ++k) acc += gf[(size_t)g * 6 + k] * gW[k * 64 + j];
        sComb[64 + j] = fmaxf(acc, 0.f);
    }
    __syncthreads();
    if (t < 64) {
        float acc = h1b[t];
#pragma unroll
        for (int k = 0; k < 128; ++k) acc += sComb[k] * h1W[k * 64 + t];
        sHid[t] = fmaxf(acc, 0.f);
    }
    __syncthreads();
    if (t < 64) {
        float p = sHid[t] * h2W[t];
#pragma unroll
        for (int off = 32; off > 0; off >>= 1) p += __shfl_xor(p, off, 64);
        if (t == 0) out[g] = p + h2b[0];
    }
}

extern "C" void kernel_launch(void* const* d_in, const int* in_sizes, int n_in,
                              void* d_out, int out_size, void* d_ws, size_t ws_size,
                              hipStream_t stream) {
    const float* x         = (const float*)d_in[0];
    const int*   node_type = (const int*)d_in[1];
    const int*   edge_index= (const int*)d_in[2];
    const float* edge_attr = (const float*)d_in[3];
    const int*   batch     = (const int*)d_in[4];
    const float* gf        = (const float*)d_in[5];
    const float* type_emb  = (const float*)d_in[6];
    const float* enc_W     = (const float*)d_in[7];
    const float* enc_b     = (const float*)d_in[8];
    const float* Wl        = (const float*)d_in[9];
    const float* bl        = (const float*)d_in[10];
    const float* Wr        = (const float*)d_in[11];
    const float* br        = (const float*)d_in[12];
    const float* We        = (const float*)d_in[13];
    const float* att       = (const float*)d_in[14];
    const float* conv_bias = (const float*)d_in[15];
    const float* gW        = (const float*)d_in[16];
    const float* gb        = (const float*)d_in[17];
    const float* h1W       = (const float*)d_in[18];
    const float* h1b       = (const float*)d_in[19];
    const float* h2W       = (const float*)d_in[20];
    const float* h2b       = (const float*)d_in[21];
    float* out = (float*)d_out;

    const int N = in_sizes[0] / 6;
    const int E = in_sizes[2] / 2;
    const int G = in_sizes[5] / 6;

    const int* srcArr = edge_index;
    const int* dstArr = edge_index + E;

    // workspace layout
    char* wsb = (char*)d_ws;
    size_t off = 0;
    float* xl        = (float*)(wsb + off); off += (size_t)N * 256 * 4;
    float* xr        = (float*)(wsb + off); off += (size_t)N * 256 * 4;
    float* loop_attr = (float*)(wsb + off); off += (size_t)N * 11 * 4;
    int*   row_ptr   = (int*)  (wsb + off); off += (size_t)(N + 1) * 4;
    int*   eidx      = (int*)  (wsb + off); off += (size_t)E * 4;
    size_t zs = off;  // ---- zeroed region starts here ----
    float* attr_sum  = (float*)(wsb + off); off += (size_t)N * 11 * 4;
    int*   degi      = (int*)  (wsb + off); off += (size_t)N * 4;
    int*   cursor    = (int*)  (wsb + off); off += (size_t)N * 4;
    float* pooled    = (float*)(wsb + off); off += (size_t)G * 64 * 4;
    float* gcnt      = (float*)(wsb + off); off += (size_t)G * 4;
    size_t ze = off;
    (void)ws_size; (void)n_in; (void)out_size;

    hipMemsetAsync(wsb + zs, 0, ze - zs, stream);

    k_hist_accum<<<(E + 255) / 256, 256, 0, stream>>>(dstArr, edge_attr, attr_sum, degi, E);
    k_enc_xlxr<<<(N + 15) / 16, 256, 0, stream>>>(x, node_type, type_emb, enc_W, enc_b,
                                                  Wl, bl, Wr, br, xl, xr, N);
    k_scan<<<1, 1024, 0, stream>>>(degi, row_ptr, N);
    k_fill<<<(E + 255) / 256, 256, 0, stream>>>(dstArr, row_ptr, cursor, eidx, E);
    k_loop_attr<<<(N + 255) / 256, 256, 0, stream>>>(attr_sum, degi, loop_attr, N);
    k_gather<<<(N + 3) / 4, 256, 0, stream>>>(srcArr, edge_attr, loop_attr, row_ptr, eidx,
                                              We, att, xl, xr, conv_bias, batch,
                                              pooled, gcnt, N);
    k_final<<<G, 128, 0, stream>>>(pooled, gcnt, gf, gW, gb, h1W, h1b, h2W, h2b, out, G);
}

// Round 5
// 897.900 us; speedup vs baseline: 2.6333x; 1.5756x over previous
//
#include <hip/hip_runtime.h>

#define NEG_SLOPE 0.2f

// ---------------- K1: degree histogram ----------------
__global__ void k_deg(const int* __restrict__ dst, int* __restrict__ degi, int E) {
    int e = blockIdx.x * blockDim.x + threadIdx.x;
    if (e >= E) return;
    atomicAdd(&degi[dst[e]], 1);
}

// ---------------- K2: single-block exclusive scan of degrees -> row_ptr (+cursor copy) ----------------
__global__ void __launch_bounds__(1024) k_scan(const int* __restrict__ degi,
                                               int* __restrict__ row_ptr,
                                               int* __restrict__ cursor, int N) {
    __shared__ int wsum[16];
    __shared__ int srun;
    int tid = threadIdx.x, lane = tid & 63, wid = tid >> 6;
    if (tid == 0) srun = 0;
    __syncthreads();
    for (int base = 0; base < N; base += 1024) {
        int i = base + tid;
        int v = (i < N) ? degi[i] : 0;
        int x = v;
#pragma unroll
        for (int off = 1; off < 64; off <<= 1) {
            int y = __shfl_up(x, off, 64);
            if (lane >= off) x += y;
        }
        if (lane == 63) wsum[wid] = x;
        __syncthreads();
        if (wid == 0) {
            int w = (lane < 16) ? wsum[lane] : 0;
#pragma unroll
            for (int off = 1; off < 16; off <<= 1) {
                int y = __shfl_up(w, off, 64);
                if (lane >= off) w += y;
            }
            if (lane < 16) wsum[lane] = w;  // inclusive wave sums
        }
        __syncthreads();
        int wofs = (wid > 0) ? wsum[wid - 1] : 0;
        int run = srun;
        if (i < N) {
            int ex = run + wofs + x - v;  // exclusive prefix
            row_ptr[i] = ex;
            cursor[i] = ex;
        }
        __syncthreads();
        if (tid == 1023) srun = run + wsum[15];
        __syncthreads();
    }
    if (tid == 0) row_ptr[N] = srun;
}

// ---------------- K3: CSR fill with (src, edge_id) pairs ----------------
__global__ void k_fill(const int* __restrict__ src, const int* __restrict__ dst,
                       int* __restrict__ cursor, int2* __restrict__ csr, int E) {
    int e = blockIdx.x * blockDim.x + threadIdx.x;
    if (e >= E) return;
    int d = dst[e];
    int pos = atomicAdd(&cursor[d], 1);
    csr[pos] = make_int2(src[e], e);
}

// ---------------- K4: fused node encoder + xl/xr transforms ----------------
__global__ void __launch_bounds__(256) k_enc_xlxr(
    const float* __restrict__ x, const int* __restrict__ node_type,
    const float* __restrict__ type_emb,
    const float* __restrict__ enc_W, const float* __restrict__ enc_b,
    const float* __restrict__ Wl, const float* __restrict__ bl,
    const float* __restrict__ Wr, const float* __restrict__ br,
    float* __restrict__ xl, float* __restrict__ xr, int N) {
    const int NPB = 16;
    __shared__ float sIn[NPB][10];
    __shared__ float sH[NPB][64];
    int tid = threadIdx.x;
    int v0 = blockIdx.x * NPB;
    for (int i = tid; i < NPB * 10; i += 256) {
        int v = i / 10, k = i % 10;
        int vg = v0 + v;
        float val = 0.f;
        if (vg < N) {
            if (k < 6) val = x[(size_t)vg * 6 + k];
            else       val = type_emb[node_type[vg] * 4 + (k - 6)];
        }
        sIn[v][k] = val;
    }
    __syncthreads();
    for (int i = tid; i < NPB * 64; i += 256) {
        int v = i >> 6, j = i & 63;
        float acc = enc_b[j];
#pragma unroll
        for (int k = 0; k < 10; ++k) acc += sIn[v][k] * enc_W[k * 64 + j];
        sH[v][j] = fmaxf(acc, 0.f);
    }
    __syncthreads();
    int j = tid;
    float accL[NPB], accR[NPB];
    float blj = bl[j], brj = br[j];
#pragma unroll
    for (int v = 0; v < NPB; ++v) { accL[v] = blj; accR[v] = brj; }
    for (int k = 0; k < 64; ++k) {
        float wl = Wl[k * 256 + j], wr = Wr[k * 256 + j];
#pragma unroll
        for (int v = 0; v < NPB; ++v) {
            float hv = sH[v][k];
            accL[v] += hv * wl;
            accR[v] += hv * wr;
        }
    }
#pragma unroll
    for (int v = 0; v < NPB; ++v) {
        int vg = v0 + v;
        if (vg < N) {
            xl[(size_t)vg * 256 + j] = accL[v];
            xr[(size_t)vg * 256 + j] = accR[v];
        }
    }
}

// ---------------- K5: fused per-node GATv2 (one wave/node; 16 lanes/head; We in VGPRs) ----------------
__global__ void __launch_bounds__(256, 4) k_gather(
    const int2* __restrict__ csr, const float* __restrict__ edge_attr,
    const int* __restrict__ row_ptr, const float* __restrict__ We,
    const float* __restrict__ att, const float* __restrict__ xl,
    const float* __restrict__ xr, const float* __restrict__ conv_bias,
    const int* __restrict__ batch, float* __restrict__ pooled,
    float* __restrict__ gcnt, int N) {
    int tid = threadIdx.x;
    int lane = tid & 63;
    int h = lane >> 4;           // head 0..3
    int c16 = lane & 15;
    int colBase = h * 64 + c16 * 4;  // 4 consecutive cols of my head
    int v = blockIdx.x * 4 + (tid >> 6);
    if (v >= N) return;

    // register-resident weight slices
    float rWe[11][4];
#pragma unroll
    for (int k = 0; k < 11; ++k) {
        float4 w = *(const float4*)(We + k * 256 + colBase);
        rWe[k][0] = w.x; rWe[k][1] = w.y; rWe[k][2] = w.z; rWe[k][3] = w.w;
    }
    float4 attv = *(const float4*)(att + colBase);
    float4 xrv  = *(const float4*)(xr + (size_t)v * 256 + colBase);

    float acc0 = 0.f, acc1 = 0.f, acc2 = 0.f, acc3 = 0.f, den = 0.f;
    float ea0 = 0.f, ea1 = 0.f, ea2 = 0.f, ea3 = 0.f;  // ee accumulator (for self-loop mean)

    int rs = row_ptr[v], re = row_ptr[v + 1];
    int deg = re - rs;

    auto process = [&](const float (&a)[11], float4 xlv) {
        float e0 = 0.f, e1 = 0.f, e2 = 0.f, e3 = 0.f;
#pragma unroll
        for (int k = 0; k < 11; ++k) {
            e0 += a[k] * rWe[k][0]; e1 += a[k] * rWe[k][1];
            e2 += a[k] * rWe[k][2]; e3 += a[k] * rWe[k][3];
        }
        ea0 += e0; ea1 += e1; ea2 += e2; ea3 += e3;
        float m0 = xlv.x + xrv.x + e0;
        float m1 = xlv.y + xrv.y + e1;
        float m2 = xlv.z + xrv.z + e2;
        float m3 = xlv.w + xrv.w + e3;
        m0 = (m0 > 0.f) ? m0 : NEG_SLOPE * m0;
        m1 = (m1 > 0.f) ? m1 : NEG_SLOPE * m1;
        m2 = (m2 > 0.f) ? m2 : NEG_SLOPE * m2;
        m3 = (m3 > 0.f) ? m3 : NEG_SLOPE * m3;
        float t2 = m0 * attv.x + m1 * attv.y + m2 * attv.z + m3 * attv.w;
#pragma unroll
        for (int off = 1; off < 16; off <<= 1) t2 += __shfl_xor(t2, off, 64);
        float p = __expf(t2);
        acc0 += p * xlv.x; acc1 += p * xlv.y; acc2 += p * xlv.z; acc3 += p * xlv.w;
        den += p;
    };

    for (int base = rs; base < re; base += 64) {
        int cnt = re - base; if (cnt > 64) cnt = 64;
        int2 se = csr[base + ((lane < cnt) ? lane : 0)];
        int myS = se.x, myE = se.y;

        float aA[11], aB[11];
        float4 xA, xB;
        {   // prefetch t = 0
            int s = __builtin_amdgcn_readfirstlane(__shfl(myS, 0, 64));
            int e = __builtin_amdgcn_readfirstlane(__shfl(myE, 0, 64));
            const float* ap = edge_attr + (size_t)e * 11;
#pragma unroll
            for (int k = 0; k < 11; ++k) aA[k] = ap[k];
            xA = *(const float4*)(xl + (size_t)s * 256 + colBase);
        }
        int t = 0;
        while (true) {
            if (t + 1 < cnt) {  // prefetch t+1 into B
                int s = __builtin_amdgcn_readfirstlane(__shfl(myS, t + 1, 64));
                int e = __builtin_amdgcn_readfirstlane(__shfl(myE, t + 1, 64));
                const float* ap = edge_attr + (size_t)e * 11;
#pragma unroll
                for (int k = 0; k < 11; ++k) aB[k] = ap[k];
                xB = *(const float4*)(xl + (size_t)s * 256 + colBase);
            }
            process(aA, xA);
            ++t; if (t >= cnt) break;
            if (t + 1 < cnt) {  // prefetch t+2 into A
                int s = __builtin_amdgcn_readfirstlane(__shfl(myS, t + 1, 64));
                int e = __builtin_amdgcn_readfirstlane(__shfl(myE, t + 1, 64));
                const float* ap = edge_attr + (size_t)e * 11;
#pragma unroll
                for (int k = 0; k < 11; ++k) aA[k] = ap[k];
                xA = *(const float4*)(xl + (size_t)s * 256 + colBase);
            }
            process(aB, xB);
            ++t; if (t >= cnt) break;
        }
    }

    // self-loop: attrs = mean of incoming edge attrs; ee is linear -> use eeacc/deg
    {
        float inv = 1.f / fmaxf((float)deg, 1.f);
        float4 xself = *(const float4*)(xl + (size_t)v * 256 + colBase);
        float e0 = ea0 * inv, e1 = ea1 * inv, e2 = ea2 * inv, e3 = ea3 * inv;
        float m0 = xself.x + xrv.x + e0;
        float m1 = xself.y + xrv.y + e1;
        float m2 = xself.z + xrv.z + e2;
        float m3 = xself.w + xrv.w + e3;
        m0 = (m0 > 0.f) ? m0 : NEG_SLOPE * m0;
        m1 = (m1 > 0.f) ? m1 : NEG_SLOPE * m1;
        m2 = (m2 > 0.f) ? m2 : NEG_SLOPE * m2;
        m3 = (m3 > 0.f) ? m3 : NEG_SLOPE * m3;
        float t2 = m0 * attv.x + m1 * attv.y + m2 * attv.z + m3 * attv.w;
#pragma unroll
        for (int off = 1; off < 16; off <<= 1) t2 += __shfl_xor(t2, off, 64);
        float p = __expf(t2);
        acc0 += p * xself.x; acc1 += p * xself.y; acc2 += p * xself.z; acc3 += p * xself.w;
        den += p;
    }

    float r = 1.f / (den + 1e-16f);
    float o0 = acc0 * r, o1 = acc1 * r, o2 = acc2 * r, o3 = acc3 * r;
    // head-sum butterfly (lanes lane^16, lane^32, lane^48 hold other heads' same cols)
#pragma unroll
    for (int mask = 16; mask <= 32; mask <<= 1) {
        o0 += __shfl_xor(o0, mask, 64);
        o1 += __shfl_xor(o1, mask, 64);
        o2 += __shfl_xor(o2, mask, 64);
        o3 += __shfl_xor(o3, mask, 64);
    }
    int g = batch[v];
    if (lane < 16) {
        float4 cb = *(const float4*)(conv_bias + c16 * 4);
        float* pg = pooled + g * 64 + c16 * 4;
        atomicAdd(&pg[0], fmaxf(0.25f * o0 + cb.x, 0.f));
        atomicAdd(&pg[1], fmaxf(0.25f * o1 + cb.y, 0.f));
        atomicAdd(&pg[2], fmaxf(0.25f * o2 + cb.z, 0.f));
        atomicAdd(&pg[3], fmaxf(0.25f * o3 + cb.w, 0.f));
    }
    if (lane == 0) atomicAdd(&gcnt[g], 1.0f);
}

// ---------------- K6: per-graph MLP head ----------------
__global__ void k_final(const float* __restrict__ pooled, const float* __restrict__ gcnt,
                        const float* __restrict__ gf, const float* __restrict__ gW,
                        const float* __restrict__ gb, const float* __restrict__ h1W,
                        const float* __restrict__ h1b, const float* __restrict__ h2W,
                        const float* __restrict__ h2b, float* __restrict__ out, int G) {
    __shared__ float sComb[128];
    __shared__ float sHid[64];
    int g = blockIdx.x;
    int t = threadIdx.x;
    if (t < 64) {
        sComb[t] = pooled[(size_t)g * 64 + t] / fmaxf(gcnt[g], 1.0f);
    } else {
        int j = t - 64;
        float acc = gb[j];
#pragma unroll
        for (int k = 0; k < 6; ++k) acc += gf[(size_t)g * 6 + k] * gW[k * 64 + j];
        sComb[64 + j] = fmaxf(acc, 0.f);
    }
    __syncthreads();
    if (t < 64) {
        float acc = h1b[t];
#pragma unroll
        for (int k = 0; k < 128; ++k) acc += sComb[k] * h1W[k * 64 + t];
        sHid[t] = fmaxf(acc, 0.f);
    }
    __syncthreads();
    if (t < 64) {
        float p = sHid[t] * h2W[t];
#pragma unroll
        for (int off = 32; off > 0; off >>= 1) p += __shfl_xor(p, off, 64);
        if (t == 0) out[g] = p + h2b[0];
    }
}

extern "C" void kernel_launch(void* const* d_in, const int* in_sizes, int n_in,
                              void* d_out, int out_size, void* d_ws, size_t ws_size,
                              hipStream_t stream) {
    const float* x         = (const float*)d_in[0];
    const int*   node_type = (const int*)d_in[1];
    const int*   edge_index= (const int*)d_in[2];
    const float* edge_attr = (const float*)d_in[3];
    const int*   batch     = (const int*)d_in[4];
    const float* gf        = (const float*)d_in[5];
    const float* type_emb  = (const float*)d_in[6];
    const float* enc_W     = (const float*)d_in[7];
    const float* enc_b     = (const float*)d_in[8];
    const float* Wl        = (const float*)d_in[9];
    const float* bl        = (const float*)d_in[10];
    const float* Wr        = (const float*)d_in[11];
    const float* br        = (const float*)d_in[12];
    const float* We        = (const float*)d_in[13];
    const float* att       = (const float*)d_in[14];
    const float* conv_bias = (const float*)d_in[15];
    const float* gW        = (const float*)d_in[16];
    const float* gb        = (const float*)d_in[17];
    const float* h1W       = (const float*)d_in[18];
    const float* h1b       = (const float*)d_in[19];
    const float* h2W       = (const float*)d_in[20];
    const float* h2b       = (const float*)d_in[21];
    float* out = (float*)d_out;

    const int N = in_sizes[0] / 6;
    const int E = in_sizes[2] / 2;
    const int G = in_sizes[5] / 6;

    const int* srcArr = edge_index;
    const int* dstArr = edge_index + E;

    // workspace layout
    char* wsb = (char*)d_ws;
    size_t off = 0;
    float* xl      = (float*)(wsb + off); off += (size_t)N * 256 * 4;
    float* xr      = (float*)(wsb + off); off += (size_t)N * 256 * 4;
    int2*  csr     = (int2*) (wsb + off); off += (size_t)E * 8;
    int*   row_ptr = (int*)  (wsb + off); off += (size_t)(N + 1) * 4;
    int*   cursor  = (int*)  (wsb + off); off += (size_t)N * 4;
    size_t zs = off;  // ---- zeroed region ----
    int*   degi    = (int*)  (wsb + off); off += (size_t)N * 4;
    float* pooled  = (float*)(wsb + off); off += (size_t)G * 64 * 4;
    float* gcnt    = (float*)(wsb + off); off += (size_t)G * 4;
    size_t ze = off;
    (void)ws_size; (void)n_in; (void)out_size;

    hipMemsetAsync(wsb + zs, 0, ze - zs, stream);

    k_deg<<<(E + 255) / 256, 256, 0, stream>>>(dstArr, degi, E);
    k_enc_xlxr<<<(N + 15) / 16, 256, 0, stream>>>(x, node_type, type_emb, enc_W, enc_b,
                                                  Wl, bl, Wr, br, xl, xr, N);
    k_scan<<<1, 1024, 0, stream>>>(degi, row_ptr, cursor, N);
    k_fill<<<(E + 255) / 256, 256, 0, stream>>>(srcArr, dstArr, cursor, csr, E);
    k_gather<<<(N + 3) / 4, 256, 0, stream>>>(csr, edge_attr, row_ptr, We, att, xl, xr,
                                              conv_bias, batch, pooled, gcnt, N);
    k_final<<<G, 128, 0, stream>>>(pooled, gcnt, gf, gW, gb, h1W, h1b, h2W, h2b, out, G);
}

// Round 6
// 836.813 us; speedup vs baseline: 2.8256x; 1.0730x over previous
//
#include <hip/hip_runtime.h>

#define NEG_SLOPE 0.2f

__device__ __forceinline__ float rl(float v, int l) {
    return __uint_as_float(__builtin_amdgcn_readlane(__float_as_uint(v), l));
}

// ---------------- K1: degree histogram ----------------
__global__ void k_deg(const int* __restrict__ dst, int* __restrict__ degi, int E) {
    int e = blockIdx.x * blockDim.x + threadIdx.x;
    if (e >= E) return;
    atomicAdd(&degi[dst[e]], 1);
}

// ---------------- K2: single-block exclusive scan of degrees -> row_ptr (+cursor copy) ----------------
__global__ void __launch_bounds__(1024) k_scan(const int* __restrict__ degi,
                                               int* __restrict__ row_ptr,
                                               int* __restrict__ cursor, int N) {
    __shared__ int wsum[16];
    __shared__ int srun;
    int tid = threadIdx.x, lane = tid & 63, wid = tid >> 6;
    if (tid == 0) srun = 0;
    __syncthreads();
    for (int base = 0; base < N; base += 1024) {
        int i = base + tid;
        int v = (i < N) ? degi[i] : 0;
        int x = v;
#pragma unroll
        for (int off = 1; off < 64; off <<= 1) {
            int y = __shfl_up(x, off, 64);
            if (lane >= off) x += y;
        }
        if (lane == 63) wsum[wid] = x;
        __syncthreads();
        if (wid == 0) {
            int w = (lane < 16) ? wsum[lane] : 0;
#pragma unroll
            for (int off = 1; off < 16; off <<= 1) {
                int y = __shfl_up(w, off, 64);
                if (lane >= off) w += y;
            }
            if (lane < 16) wsum[lane] = w;  // inclusive wave sums
        }
        __syncthreads();
        int wofs = (wid > 0) ? wsum[wid - 1] : 0;
        int run = srun;
        if (i < N) {
            int ex = run + wofs + x - v;  // exclusive prefix
            row_ptr[i] = ex;
            cursor[i] = ex;
        }
        __syncthreads();
        if (tid == 1023) srun = run + wsum[15];
        __syncthreads();
    }
    if (tid == 0) row_ptr[N] = srun;
}

// ---------------- K3: CSR fill with (src, edge_id) pairs ----------------
__global__ void k_fill(const int* __restrict__ src, const int* __restrict__ dst,
                       int* __restrict__ cursor, int2* __restrict__ csr, int E) {
    int e = blockIdx.x * blockDim.x + threadIdx.x;
    if (e >= E) return;
    int d = dst[e];
    int pos = atomicAdd(&cursor[d], 1);
    csr[pos] = make_int2(src[e], e);
}

// ---------------- K4: fused node encoder + xl/xr transforms ----------------
__global__ void __launch_bounds__(256) k_enc_xlxr(
    const float* __restrict__ x, const int* __restrict__ node_type,
    const float* __restrict__ type_emb,
    const float* __restrict__ enc_W, const float* __restrict__ enc_b,
    const float* __restrict__ Wl, const float* __restrict__ bl,
    const float* __restrict__ Wr, const float* __restrict__ br,
    float* __restrict__ xl, float* __restrict__ xr, int N) {
    const int NPB = 16;
    __shared__ float sIn[NPB][10];
    __shared__ float sH[NPB][64];
    int tid = threadIdx.x;
    int v0 = blockIdx.x * NPB;
    for (int i = tid; i < NPB * 10; i += 256) {
        int v = i / 10, k = i % 10;
        int vg = v0 + v;
        float val = 0.f;
        if (vg < N) {
            if (k < 6) val = x[(size_t)vg * 6 + k];
            else       val = type_emb[node_type[vg] * 4 + (k - 6)];
        }
        sIn[v][k] = val;
    }
    __syncthreads();
    for (int i = tid; i < NPB * 64; i += 256) {
        int v = i >> 6, j = i & 63;
        float acc = enc_b[j];
#pragma unroll
        for (int k = 0; k < 10; ++k) acc += sIn[v][k] * enc_W[k * 64 + j];
        sH[v][j] = fmaxf(acc, 0.f);
    }
    __syncthreads();
    int j = tid;
    float accL[NPB], accR[NPB];
    float blj = bl[j], brj = br[j];
#pragma unroll
    for (int v = 0; v < NPB; ++v) { accL[v] = blj; accR[v] = brj; }
    for (int k = 0; k < 64; ++k) {
        float wl = Wl[k * 256 + j], wr = Wr[k * 256 + j];
#pragma unroll
        for (int v = 0; v < NPB; ++v) {
            float hv = sH[v][k];
            accL[v] += hv * wl;
            accR[v] += hv * wr;
        }
    }
#pragma unroll
    for (int v = 0; v < NPB; ++v) {
        int vg = v0 + v;
        if (vg < N) {
            xl[(size_t)vg * 256 + j] = accL[v];
            xr[(size_t)vg * 256 + j] = accR[v];
        }
    }
}

// ---------------- K5: fused per-node GATv2; batch-4 edges, A/B double-buffered ----------------
__global__ void __launch_bounds__(256, 4) k_gather(
    const int2* __restrict__ csr, const float* __restrict__ edge_attr,
    const int* __restrict__ row_ptr, const float* __restrict__ We,
    const float* __restrict__ att, const float* __restrict__ xl,
    const float* __restrict__ xr, const float* __restrict__ conv_bias,
    const int* __restrict__ batch, float* __restrict__ pooled,
    float* __restrict__ gcnt, int N) {
    int tid = threadIdx.x;
    int lane = tid & 63;
    int h = lane >> 4;           // head 0..3
    int c16 = lane & 15;
    int colBase = h * 64 + c16 * 4;  // 4 consecutive cols of my head
    int v = blockIdx.x * 4 + (tid >> 6);
    if (v >= N) return;

    // register-resident weight slices
    float rWe[11][4];
#pragma unroll
    for (int k = 0; k < 11; ++k) {
        float4 w = *(const float4*)(We + k * 256 + colBase);
        rWe[k][0] = w.x; rWe[k][1] = w.y; rWe[k][2] = w.z; rWe[k][3] = w.w;
    }
    float4 attv = *(const float4*)(att + colBase);
    float4 xrv  = *(const float4*)(xr + (size_t)v * 256 + colBase);

    float acc0 = 0.f, acc1 = 0.f, acc2 = 0.f, acc3 = 0.f, den = 0.f;
    float ea0 = 0.f, ea1 = 0.f, ea2 = 0.f, ea3 = 0.f;  // ee accumulator (self-loop mean)

    int rs = row_ptr[v], re = row_ptr[v + 1];
    int deg = re - rs;
    int attrLaneC = lane / 11; if (attrLaneC > 3) attrLaneC = 3;  // which edge-in-batch this lane stages
    int attrLaneK = lane - attrLaneC * 11;                        // which attr element

    for (int base = rs; base < re; base += 64) {
        int cnt = re - base; if (cnt > 64) cnt = 64;
        int cm1 = cnt - 1;
        int2 se = csr[base + ((lane < cnt) ? lane : 0)];
        int myS = se.x, myE = se.y;

        // LOADB: stage batch starting at t0 into (attr, x0..x3)
        auto LOADB = [&](int t0, float& attrR, float4& x0, float4& x1, float4& x2, float4& x3) {
            int ei = t0 + attrLaneC; if (ei > cm1) ei = cm1;
            int eL = __shfl(myE, ei, 64);
            float a = 0.f;
            if (lane < 44) a = edge_attr[(size_t)eL * 11 + attrLaneK];
            attrR = a;
            int i1 = t0 + 1; if (i1 > cm1) i1 = cm1;
            int i2 = t0 + 2; if (i2 > cm1) i2 = cm1;
            int i3 = t0 + 3; if (i3 > cm1) i3 = cm1;
            int s0 = __builtin_amdgcn_readfirstlane(__shfl(myS, t0, 64));
            int s1 = __builtin_amdgcn_readfirstlane(__shfl(myS, i1, 64));
            int s2 = __builtin_amdgcn_readfirstlane(__shfl(myS, i2, 64));
            int s3 = __builtin_amdgcn_readfirstlane(__shfl(myS, i3, 64));
            x0 = *(const float4*)(xl + (size_t)s0 * 256 + colBase);
            x1 = *(const float4*)(xl + (size_t)s1 * 256 + colBase);
            x2 = *(const float4*)(xl + (size_t)s2 * 256 + colBase);
            x3 = *(const float4*)(xl + (size_t)s3 * 256 + colBase);
        };

        auto EDGE = [&](float attrR, float4 xlv, int cbase) {
            float e0 = 0.f, e1 = 0.f, e2 = 0.f, e3 = 0.f;
#pragma unroll
            for (int k = 0; k < 11; ++k) {
                float s = rl(attrR, cbase + k);
                e0 += s * rWe[k][0]; e1 += s * rWe[k][1];
                e2 += s * rWe[k][2]; e3 += s * rWe[k][3];
            }
            ea0 += e0; ea1 += e1; ea2 += e2; ea3 += e3;
            float m0 = xlv.x + xrv.x + e0;
            float m1 = xlv.y + xrv.y + e1;
            float m2 = xlv.z + xrv.z + e2;
            float m3 = xlv.w + xrv.w + e3;
            m0 = (m0 > 0.f) ? m0 : NEG_SLOPE * m0;
            m1 = (m1 > 0.f) ? m1 : NEG_SLOPE * m1;
            m2 = (m2 > 0.f) ? m2 : NEG_SLOPE * m2;
            m3 = (m3 > 0.f) ? m3 : NEG_SLOPE * m3;
            float t2 = m0 * attv.x + m1 * attv.y + m2 * attv.z + m3 * attv.w;
#pragma unroll
            for (int off = 1; off < 16; off <<= 1) t2 += __shfl_xor(t2, off, 64);
            float p = __expf(t2);
            acc0 += p * xlv.x; acc1 += p * xlv.y; acc2 += p * xlv.z; acc3 += p * xlv.w;
            den += p;
        };

        auto PROC = [&](int t0, float attrR, float4 x0, float4 x1, float4 x2, float4 x3) {
            EDGE(attrR, x0, 0);
            if (t0 + 1 < cnt) EDGE(attrR, x1, 11);
            if (t0 + 2 < cnt) EDGE(attrR, x2, 22);
            if (t0 + 3 < cnt) EDGE(attrR, x3, 33);
        };

        int nb = (cnt + 3) >> 2;
        float attrA, attrB;
        float4 xA0, xA1, xA2, xA3, xB0, xB1, xB2, xB3;
        LOADB(0, attrA, xA0, xA1, xA2, xA3);
        int b = 0;
        while (true) {
            if (b + 1 < nb) LOADB((b + 1) * 4, attrB, xB0, xB1, xB2, xB3);
            PROC(b * 4, attrA, xA0, xA1, xA2, xA3);
            ++b; if (b >= nb) break;
            if (b + 1 < nb) LOADB((b + 1) * 4, attrA, xA0, xA1, xA2, xA3);
            PROC(b * 4, attrB, xB0, xB1, xB2, xB3);
            ++b; if (b >= nb) break;
        }
    }

    // self-loop: attrs = mean of incoming edge attrs; ee linear -> eeacc/deg
    {
        float inv = 1.f / fmaxf((float)deg, 1.f);
        float4 xself = *(const float4*)(xl + (size_t)v * 256 + colBase);
        float e0 = ea0 * inv, e1 = ea1 * inv, e2 = ea2 * inv, e3 = ea3 * inv;
        float m0 = xself.x + xrv.x + e0;
        float m1 = xself.y + xrv.y + e1;
        float m2 = xself.z + xrv.z + e2;
        float m3 = xself.w + xrv.w + e3;
        m0 = (m0 > 0.f) ? m0 : NEG_SLOPE * m0;
        m1 = (m1 > 0.f) ? m1 : NEG_SLOPE * m1;
        m2 = (m2 > 0.f) ? m2 : NEG_SLOPE * m2;
        m3 = (m3 > 0.f) ? m3 : NEG_SLOPE * m3;
        float t2 = m0 * attv.x + m1 * attv.y + m2 * attv.z + m3 * attv.w;
#pragma unroll
        for (int off = 1; off < 16; off <<= 1) t2 += __shfl_xor(t2, off, 64);
        float p = __expf(t2);
        acc0 += p * xself.x; acc1 += p * xself.y; acc2 += p * xself.z; acc3 += p * xself.w;
        den += p;
    }

    float r = 1.f / (den + 1e-16f);
    float o0 = acc0 * r, o1 = acc1 * r, o2 = acc2 * r, o3 = acc3 * r;
    // head-sum butterfly
#pragma unroll
    for (int mask = 16; mask <= 32; mask <<= 1) {
        o0 += __shfl_xor(o0, mask, 64);
        o1 += __shfl_xor(o1, mask, 64);
        o2 += __shfl_xor(o2, mask, 64);
        o3 += __shfl_xor(o3, mask, 64);
    }
    int g = batch[v];
    if (lane < 16) {
        float4 cb = *(const float4*)(conv_bias + c16 * 4);
        float* pg = pooled + g * 64 + c16 * 4;
        atomicAdd(&pg[0], fmaxf(0.25f * o0 + cb.x, 0.f));
        atomicAdd(&pg[1], fmaxf(0.25f * o1 + cb.y, 0.f));
        atomicAdd(&pg[2], fmaxf(0.25f * o2 + cb.z, 0.f));
        atomicAdd(&pg[3], fmaxf(0.25f * o3 + cb.w, 0.f));
    }
    if (lane == 0) atomicAdd(&gcnt[g], 1.0f);
}

// ---------------- K6: per-graph MLP head ----------------
__global__ void k_final(const float* __restrict__ pooled, const float* __restrict__ gcnt,
                        const float* __restrict__ gf, const float* __restrict__ gW,
                        const float* __restrict__ gb, const float* __restrict__ h1W,
                        const float* __restrict__ h1b, const float* __restrict__ h2W,
                        const float* __restrict__ h2b, float* __restrict__ out, int G) {
    __shared__ float sComb[128];
    __shared__ float sHid[64];
    int g = blockIdx.x;
    int t = threadIdx.x;
    if (t < 64) {
        sComb[t] = pooled[(size_t)g * 64 + t] / fmaxf(gcnt[g], 1.0f);
    } else {
        int j = t - 64;
        float acc = gb[j];
#pragma unroll
        for (int k = 0; k < 6; ++k) acc += gf[(size_t)g * 6 + k] * gW[k * 64 + j];
        sComb[64 + j] = fmaxf(acc, 0.f);
    }
    __syncthreads();
    if (t < 64) {
        float acc = h1b[t];
#pragma unroll
        for (int k = 0; k < 128; ++k) acc += sComb[k] * h1W[k * 64 + t];
        sHid[t] = fmaxf(acc, 0.f);
    }
    __syncthreads();
    if (t < 64) {
        float p = sHid[t] * h2W[t];
#pragma unroll
        for (int off = 32; off > 0; off >>= 1) p += __shfl_xor(p, off, 64);
        if (t == 0) out[g] = p + h2b[0];
    }
}

extern "C" void kernel_launch(void* const* d_in, const int* in_sizes, int n_in,
                              void* d_out, int out_size, void* d_ws, size_t ws_size,
                              hipStream_t stream) {
    const float* x         = (const float*)d_in[0];
    const int*   node_type = (const int*)d_in[1];
    const int*   edge_index= (const int*)d_in[2];
    const float* edge_attr = (const float*)d_in[3];
    const int*   batch     = (const int*)d_in[4];
    const float* gf        = (const float*)d_in[5];
    const float* type_emb  = (const float*)d_in[6];
    const float* enc_W     = (const float*)d_in[7];
    const float* enc_b     = (const float*)d_in[8];
    const float* Wl        = (const float*)d_in[9];
    const float* bl        = (const float*)d_in[10];
    const float* Wr        = (const float*)d_in[11];
    const float* br        = (const float*)d_in[12];
    const float* We        = (const float*)d_in[13];
    const float* att       = (const float*)d_in[14];
    const float* conv_bias = (const float*)d_in[15];
    const float* gW        = (const float*)d_in[16];
    const float* gb        = (const float*)d_in[17];
    const float* h1W       = (const float*)d_in[18];
    const float* h1b       = (const float*)d_in[19];
    const float* h2W       = (const float*)d_in[20];
    const float* h2b       = (const float*)d_in[21];
    float* out = (float*)d_out;

    const int N = in_sizes[0] / 6;
    const int E = in_sizes[2] / 2;
    const int G = in_sizes[5] / 6;

    const int* srcArr = edge_index;
    const int* dstArr = edge_index + E;

    // workspace layout
    char* wsb = (char*)d_ws;
    size_t off = 0;
    float* xl      = (float*)(wsb + off); off += (size_t)N * 256 * 4;
    float* xr      = (float*)(wsb + off); off += (size_t)N * 256 * 4;
    int2*  csr     = (int2*) (wsb + off); off += (size_t)E * 8;
    int*   row_ptr = (int*)  (wsb + off); off += (size_t)(N + 1) * 4;
    int*   cursor  = (int*)  (wsb + off); off += (size_t)N * 4;
    size_t zs = off;  // ---- zeroed region ----
    int*   degi    = (int*)  (wsb + off); off += (size_t)N * 4;
    float* pooled  = (float*)(wsb + off); off += (size_t)G * 64 * 4;
    float* gcnt    = (float*)(wsb + off); off += (size_t)G * 4;
    size_t ze = off;
    (void)ws_size; (void)n_in; (void)out_size;

    hipMemsetAsync(wsb + zs, 0, ze - zs, stream);

    k_deg<<<(E + 255) / 256, 256, 0, stream>>>(dstArr, degi, E);
    k_enc_xlxr<<<(N + 15) / 16, 256, 0, stream>>>(x, node_type, type_emb, enc_W, enc_b,
                                                  Wl, bl, Wr, br, xl, xr, N);
    k_scan<<<1, 1024, 0, stream>>>(degi, row_ptr, cursor, N);
    k_fill<<<(E + 255) / 256, 256, 0, stream>>>(srcArr, dstArr, cursor, csr, E);
    k_gather<<<(N + 3) / 4, 256, 0, stream>>>(csr, edge_attr, row_ptr, We, att, xl, xr,
                                              conv_bias, batch, pooled, gcnt, N);
    k_final<<<G, 128, 0, stream>>>(pooled, gcnt, gf, gW, gb, h1W, h1b, h2W, h2b, out, G);
}

// Round 7
// 781.652 us; speedup vs baseline: 3.0250x; 1.0706x over previous
//
#include <hip/hip_runtime.h>

#define NEG_SLOPE 0.2f

__device__ __forceinline__ float rl(float v, int l) {
    return __uint_as_float(__builtin_amdgcn_readlane(__float_as_uint(v), l));
}

// ---------------- K1: degree histogram ----------------
__global__ void k_deg(const int* __restrict__ dst, int* __restrict__ degi, int E) {
    int e = blockIdx.x * blockDim.x + threadIdx.x;
    if (e >= E) return;
    atomicAdd(&degi[dst[e]], 1);
}

// ---------------- K2a: per-block scan (1024 elems/block) ----------------
__global__ void __launch_bounds__(1024) k_scan1(const int* __restrict__ degi,
                                                int* __restrict__ row_ptr,
                                                int* __restrict__ bsum, int N) {
    __shared__ int wsum[16];
    int tid = threadIdx.x, lane = tid & 63, wid = tid >> 6;
    int i = blockIdx.x * 1024 + tid;
    int v = (i < N) ? degi[i] : 0;
    int x = v;
#pragma unroll
    for (int off = 1; off < 64; off <<= 1) {
        int y = __shfl_up(x, off, 64);
        if (lane >= off) x += y;
    }
    if (lane == 63) wsum[wid] = x;
    __syncthreads();
    if (wid == 0) {
        int w = (lane < 16) ? wsum[lane] : 0;
#pragma unroll
        for (int off = 1; off < 16; off <<= 1) {
            int y = __shfl_up(w, off, 64);
            if (lane >= off) w += y;
        }
        if (lane < 16) wsum[lane] = w;
    }
    __syncthreads();
    int wofs = (wid > 0) ? wsum[wid - 1] : 0;
    if (i < N) row_ptr[i] = wofs + x - v;  // block-local exclusive
    if (tid == 0) bsum[blockIdx.x] = wsum[15];
}

// ---------------- K2b: scan of block sums (<=64 blocks) ----------------
__global__ void k_scan2(int* __restrict__ bsum, int* __restrict__ row_ptr, int nb, int N) {
    int lane = threadIdx.x & 63;
    int v = (lane < nb) ? bsum[lane] : 0;
    int x = v;
#pragma unroll
    for (int off = 1; off < 64; off <<= 1) {
        int y = __shfl_up(x, off, 64);
        if (lane >= off) x += y;
    }
    if (lane < nb) bsum[lane] = x - v;  // exclusive
    if (lane == 63) row_ptr[N] = x;     // grand total
}

// ---------------- K2c: apply block offsets ----------------
__global__ void __launch_bounds__(1024) k_scan3(int* __restrict__ row_ptr,
                                                int* __restrict__ cursor,
                                                const int* __restrict__ bsum, int N) {
    int i = blockIdx.x * 1024 + threadIdx.x;
    if (i < N) {
        int r = row_ptr[i] + bsum[blockIdx.x];
        row_ptr[i] = r;
        cursor[i] = r;
    }
}

// ---------------- K3: CSR fill with (src, edge_id) pairs ----------------
__global__ void k_fill(const int* __restrict__ src, const int* __restrict__ dst,
                       int* __restrict__ cursor, int2* __restrict__ csr, int E) {
    int e = blockIdx.x * blockDim.x + threadIdx.x;
    if (e >= E) return;
    int d = dst[e];
    int pos = atomicAdd(&cursor[d], 1);
    csr[pos] = make_int2(src[e], e);
}

// ---------------- K4: fused node encoder + xl/xr transforms ----------------
__global__ void __launch_bounds__(256) k_enc_xlxr(
    const float* __restrict__ x, const int* __restrict__ node_type,
    const float* __restrict__ type_emb,
    const float* __restrict__ enc_W, const float* __restrict__ enc_b,
    const float* __restrict__ Wl, const float* __restrict__ bl,
    const float* __restrict__ Wr, const float* __restrict__ br,
    float* __restrict__ xl, float* __restrict__ xr, int N) {
    const int NPB = 16;
    __shared__ float sIn[NPB][10];
    __shared__ float sH[NPB][64];
    int tid = threadIdx.x;
    int v0 = blockIdx.x * NPB;
    for (int i = tid; i < NPB * 10; i += 256) {
        int v = i / 10, k = i % 10;
        int vg = v0 + v;
        float val = 0.f;
        if (vg < N) {
            if (k < 6) val = x[(size_t)vg * 6 + k];
            else       val = type_emb[node_type[vg] * 4 + (k - 6)];
        }
        sIn[v][k] = val;
    }
    __syncthreads();
    for (int i = tid; i < NPB * 64; i += 256) {
        int v = i >> 6, j = i & 63;
        float acc = enc_b[j];
#pragma unroll
        for (int k = 0; k < 10; ++k) acc += sIn[v][k] * enc_W[k * 64 + j];
        sH[v][j] = fmaxf(acc, 0.f);
    }
    __syncthreads();
    int j = tid;
    float accL[NPB], accR[NPB];
    float blj = bl[j], brj = br[j];
#pragma unroll
    for (int v = 0; v < NPB; ++v) { accL[v] = blj; accR[v] = brj; }
    for (int k = 0; k < 64; ++k) {
        float wl = Wl[k * 256 + j], wr = Wr[k * 256 + j];
#pragma unroll
        for (int v = 0; v < NPB; ++v) {
            float hv = sH[v][k];
            accL[v] += hv * wl;
            accR[v] += hv * wr;
        }
    }
#pragma unroll
    for (int v = 0; v < NPB; ++v) {
        int vg = v0 + v;
        if (vg < N) {
            xl[(size_t)vg * 256 + j] = accL[v];
            xr[(size_t)vg * 256 + j] = accR[v];
        }
    }
}

// ---------------- K5: fused per-node GATv2; batch-4 SoA, A/B double-buffered ----------------
__global__ void __launch_bounds__(256) __attribute__((amdgpu_waves_per_eu(3, 4)))
k_gather(
    const int2* __restrict__ csr, const float* __restrict__ edge_attr,
    const int* __restrict__ row_ptr, const float* __restrict__ We,
    const float* __restrict__ att, const float* __restrict__ xl,
    const float* __restrict__ xr, const float* __restrict__ conv_bias,
    const int* __restrict__ batch, float* __restrict__ pooled,
    float* __restrict__ gcnt, int N) {
    int tid = threadIdx.x;
    int lane = tid & 63;
    int h = lane >> 4;           // head 0..3
    int c16 = lane & 15;
    int colBase = h * 64 + c16 * 4;  // 4 consecutive cols of my head
    int v = blockIdx.x * 4 + (tid >> 6);
    if (v >= N) return;

    // register-resident weight slices
    float rWe[11][4];
#pragma unroll
    for (int k = 0; k < 11; ++k) {
        float4 w = *(const float4*)(We + k * 256 + colBase);
        rWe[k][0] = w.x; rWe[k][1] = w.y; rWe[k][2] = w.z; rWe[k][3] = w.w;
    }
    float4 attv = *(const float4*)(att + colBase);
    float4 xrv  = *(const float4*)(xr + (size_t)v * 256 + colBase);

    float acc0 = 0.f, acc1 = 0.f, acc2 = 0.f, acc3 = 0.f, den = 0.f;
    float ea0 = 0.f, ea1 = 0.f, ea2 = 0.f, ea3 = 0.f;  // ee accumulator (self-loop mean)

    int rs = row_ptr[v], re = row_ptr[v + 1];
    int deg = re - rs;
    int attrLaneC = lane / 11; if (attrLaneC > 3) attrLaneC = 3;
    int attrLaneK = lane - attrLaneC * 11;

    for (int base = rs; base < re; base += 64) {
        int cnt = re - base; if (cnt > 64) cnt = 64;
        int cm1 = cnt - 1;
        int2 se = csr[base + ((lane < cnt) ? lane : 0)];
        int myS = se.x, myE = se.y;

        auto LOADB = [&](int t0, float& attrR, float4& x0, float4& x1, float4& x2, float4& x3) {
            int ei = t0 + attrLaneC; if (ei > cm1) ei = cm1;
            int eL = __shfl(myE, ei, 64);
            float a = 0.f;
            if (lane < 44) a = edge_attr[(size_t)eL * 11 + attrLaneK];
            attrR = a;
            int i1 = t0 + 1; if (i1 > cm1) i1 = cm1;
            int i2 = t0 + 2; if (i2 > cm1) i2 = cm1;
            int i3 = t0 + 3; if (i3 > cm1) i3 = cm1;
            int s0 = __builtin_amdgcn_readlane(myS, t0);
            int s1 = __builtin_amdgcn_readlane(myS, i1);
            int s2 = __builtin_amdgcn_readlane(myS, i2);
            int s3 = __builtin_amdgcn_readlane(myS, i3);
            x0 = *(const float4*)(xl + (size_t)s0 * 256 + colBase);
            x1 = *(const float4*)(xl + (size_t)s1 * 256 + colBase);
            x2 = *(const float4*)(xl + (size_t)s2 * 256 + colBase);
            x3 = *(const float4*)(xl + (size_t)s3 * 256 + colBase);
        };

        // SoA over 4 edges: 16 independent ee chains, one shared reduction phase
        auto PROC4 = [&](int t0, float attrR, float4 x0, float4 x1, float4 x2, float4 x3) {
            float p00=0.f,p01=0.f,p02=0.f,p03=0.f;
            float p10=0.f,p11=0.f,p12=0.f,p13=0.f;
            float p20=0.f,p21=0.f,p22=0.f,p23=0.f;
            float p30=0.f,p31=0.f,p32=0.f,p33=0.f;
#pragma unroll
            for (int k = 0; k < 11; ++k) {
                float w0 = rWe[k][0], w1 = rWe[k][1], w2 = rWe[k][2], w3 = rWe[k][3];
                float s0 = rl(attrR, k), s1 = rl(attrR, 11 + k);
                float s2 = rl(attrR, 22 + k), s3 = rl(attrR, 33 + k);
                p00 += s0*w0; p01 += s0*w1; p02 += s0*w2; p03 += s0*w3;
                p10 += s1*w0; p11 += s1*w1; p12 += s1*w2; p13 += s1*w3;
                p20 += s2*w0; p21 += s2*w1; p22 += s2*w2; p23 += s2*w3;
                p30 += s3*w0; p31 += s3*w1; p32 += s3*w2; p33 += s3*w3;
            }
            bool v1 = (t0 + 1 < cnt), v2 = (t0 + 2 < cnt), v3 = (t0 + 3 < cnt);
            ea0 += p00 + (v1 ? p10 : 0.f) + (v2 ? p20 : 0.f) + (v3 ? p30 : 0.f);
            ea1 += p01 + (v1 ? p11 : 0.f) + (v2 ? p21 : 0.f) + (v3 ? p31 : 0.f);
            ea2 += p02 + (v1 ? p12 : 0.f) + (v2 ? p22 : 0.f) + (v3 ? p32 : 0.f);
            ea3 += p03 + (v1 ? p13 : 0.f) + (v2 ? p23 : 0.f) + (v3 ? p33 : 0.f);
            float m, t20, t21, t22, t23;
            m = x0.x+xrv.x+p00; m=(m>0.f)?m:NEG_SLOPE*m; t20  = m*attv.x;
            m = x0.y+xrv.y+p01; m=(m>0.f)?m:NEG_SLOPE*m; t20 += m*attv.y;
            m = x0.z+xrv.z+p02; m=(m>0.f)?m:NEG_SLOPE*m; t20 += m*attv.z;
            m = x0.w+xrv.w+p03; m=(m>0.f)?m:NEG_SLOPE*m; t20 += m*attv.w;
            m = x1.x+xrv.x+p10; m=(m>0.f)?m:NEG_SLOPE*m; t21  = m*attv.x;
            m = x1.y+xrv.y+p11; m=(m>0.f)?m:NEG_SLOPE*m; t21 += m*attv.y;
            m = x1.z+xrv.z+p12; m=(m>0.f)?m:NEG_SLOPE*m; t21 += m*attv.z;
            m = x1.w+xrv.w+p13; m=(m>0.f)?m:NEG_SLOPE*m; t21 += m*attv.w;
            m = x2.x+xrv.x+p20; m=(m>0.f)?m:NEG_SLOPE*m; t22  = m*attv.x;
            m = x2.y+xrv.y+p21; m=(m>0.f)?m:NEG_SLOPE*m; t22 += m*attv.y;
            m = x2.z+xrv.z+p22; m=(m>0.f)?m:NEG_SLOPE*m; t22 += m*attv.z;
            m = x2.w+xrv.w+p23; m=(m>0.f)?m:NEG_SLOPE*m; t22 += m*attv.w;
            m = x3.x+xrv.x+p30; m=(m>0.f)?m:NEG_SLOPE*m; t23  = m*attv.x;
            m = x3.y+xrv.y+p31; m=(m>0.f)?m:NEG_SLOPE*m; t23 += m*attv.y;
            m = x3.z+xrv.z+p32; m=(m>0.f)?m:NEG_SLOPE*m; t23 += m*attv.z;
            m = x3.w+xrv.w+p33; m=(m>0.f)?m:NEG_SLOPE*m; t23 += m*attv.w;
#pragma unroll
            for (int off = 1; off < 16; off <<= 1) {
                t20 += __shfl_xor(t20, off, 64);
                t21 += __shfl_xor(t21, off, 64);
                t22 += __shfl_xor(t22, off, 64);
                t23 += __shfl_xor(t23, off, 64);
            }
            float q0 = __expf(t20), q1 = __expf(t21), q2 = __expf(t22), q3 = __expf(t23);
            if (!v1) q1 = 0.f;
            if (!v2) q2 = 0.f;
            if (!v3) q3 = 0.f;
            acc0 += q0*x0.x; acc1 += q0*x0.y; acc2 += q0*x0.z; acc3 += q0*x0.w; den += q0;
            acc0 += q1*x1.x; acc1 += q1*x1.y; acc2 += q1*x1.z; acc3 += q1*x1.w; den += q1;
            acc0 += q2*x2.x; acc1 += q2*x2.y; acc2 += q2*x2.z; acc3 += q2*x2.w; den += q2;
            acc0 += q3*x3.x; acc1 += q3*x3.y; acc2 += q3*x3.z; acc3 += q3*x3.w; den += q3;
        };

        int nb = (cnt + 3) >> 2;
        float attrA, attrB;
        float4 xA0, xA1, xA2, xA3, xB0, xB1, xB2, xB3;
        LOADB(0, attrA, xA0, xA1, xA2, xA3);
        int b = 0;
        while (true) {
            if (b + 1 < nb) LOADB((b + 1) * 4, attrB, xB0, xB1, xB2, xB3);
            PROC4(b * 4, attrA, xA0, xA1, xA2, xA3);
            ++b; if (b >= nb) break;
            if (b + 1 < nb) LOADB((b + 1) * 4, attrA, xA0, xA1, xA2, xA3);
            PROC4(b * 4, attrB, xB0, xB1, xB2, xB3);
            ++b; if (b >= nb) break;
        }
    }

    // self-loop: attrs = mean of incoming edge attrs; ee linear -> eaacc/deg
    {
        float inv = 1.f / fmaxf((float)deg, 1.f);
        float4 xself = *(const float4*)(xl + (size_t)v * 256 + colBase);
        float e0 = ea0 * inv, e1 = ea1 * inv, e2 = ea2 * inv, e3 = ea3 * inv;
        float m0 = xself.x + xrv.x + e0;
        float m1 = xself.y + xrv.y + e1;
        float m2 = xself.z + xrv.z + e2;
        float m3 = xself.w + xrv.w + e3;
        m0 = (m0 > 0.f) ? m0 : NEG_SLOPE * m0;
        m1 = (m1 > 0.f) ? m1 : NEG_SLOPE * m1;
        m2 = (m2 > 0.f) ? m2 : NEG_SLOPE * m2;
        m3 = (m3 > 0.f) ? m3 : NEG_SLOPE * m3;
        float t2 = m0 * attv.x + m1 * attv.y + m2 * attv.z + m3 * attv.w;
#pragma unroll
        for (int off = 1; off < 16; off <<= 1) t2 += __shfl_xor(t2, off, 64);
        float p = __expf(t2);
        acc0 += p * xself.x; acc1 += p * xself.y; acc2 += p * xself.z; acc3 += p * xself.w;
        den += p;
    }

    float r = 1.f / (den + 1e-16f);
    float o0 = acc0 * r, o1 = acc1 * r, o2 = acc2 * r, o3 = acc3 * r;
#pragma unroll
    for (int mask = 16; mask <= 32; mask <<= 1) {
        o0 += __shfl_xor(o0, mask, 64);
        o1 += __shfl_xor(o1, mask, 64);
        o2 += __shfl_xor(o2, mask, 64);
        o3 += __shfl_xor(o3, mask, 64);
    }
    int g = batch[v];
    if (lane < 16) {
        float4 cb = *(const float4*)(conv_bias + c16 * 4);
        float* pg = pooled + g * 64 + c16 * 4;
        atomicAdd(&pg[0], fmaxf(0.25f * o0 + cb.x, 0.f));
        atomicAdd(&pg[1], fmaxf(0.25f * o1 + cb.y, 0.f));
        atomicAdd(&pg[2], fmaxf(0.25f * o2 + cb.z, 0.f));
        atomicAdd(&pg[3], fmaxf(0.25f * o3 + cb.w, 0.f));
    }
    if (lane == 0) atomicAdd(&gcnt[g], 1.0f);
}

// ---------------- K6: per-graph MLP head ----------------
__global__ void k_final(const float* __restrict__ pooled, const float* __restrict__ gcnt,
                        const float* __restrict__ gf, const float* __restrict__ gW,
                        const float* __restrict__ gb, const float* __restrict__ h1W,
                        const float* __restrict__ h1b, const float* __restrict__ h2W,
                        const float* __restrict__ h2b, float* __restrict__ out, int G) {
    __shared__ float sComb[128];
    __shared__ float sHid[64];
    int g = blockIdx.x;
    int t = threadIdx.x;
    if (t < 64) {
        sComb[t] = pooled[(size_t)g * 64 + t] / fmaxf(gcnt[g], 1.0f);
    } else {
        int j = t - 64;
        float acc = gb[j];
#pragma unroll
        for (int k = 0; k < 6; ++k) acc += gf[(size_t)g * 6 + k] * gW[k * 64 + j];
        sComb[64 + j] = fmaxf(acc, 0.f);
    }
    __syncthreads();
    if (t < 64) {
        float acc = h1b[t];
#pragma unroll
        for (int k = 0; k < 128; ++k) acc += sComb[k] * h1W[k * 64 + t];
        sHid[t] = fmaxf(acc, 0.f);
    }
    __syncthreads();
    if (t < 64) {
        float p = sHid[t] * h2W[t];
#pragma unroll
        for (int off = 32; off > 0; off >>= 1) p += __shfl_xor(p, off, 64);
        if (t == 0) out[g] = p + h2b[0];
    }
}

extern "C" void kernel_launch(void* const* d_in, const int* in_sizes, int n_in,
                              void* d_out, int out_size, void* d_ws, size_t ws_size,
                              hipStream_t stream) {
    const float* x         = (const float*)d_in[0];
    const int*   node_type = (const int*)d_in[1];
    const int*   edge_index= (const int*)d_in[2];
    const float* edge_attr = (const float*)d_in[3];
    const int*   batch     = (const int*)d_in[4];
    const float* gf        = (const float*)d_in[5];
    const float* type_emb  = (const float*)d_in[6];
    const float* enc_W     = (const float*)d_in[7];
    const float* enc_b     = (const float*)d_in[8];
    const float* Wl        = (const float*)d_in[9];
    const float* bl        = (const float*)d_in[10];
    const float* Wr        = (const float*)d_in[11];
    const float* br        = (const float*)d_in[12];
    const float* We        = (const float*)d_in[13];
    const float* att       = (const float*)d_in[14];
    const float* conv_bias = (const float*)d_in[15];
    const float* gW        = (const float*)d_in[16];
    const float* gb        = (const float*)d_in[17];
    const float* h1W       = (const float*)d_in[18];
    const float* h1b       = (const float*)d_in[19];
    const float* h2W       = (const float*)d_in[20];
    const float* h2b       = (const float*)d_in[21];
    float* out = (float*)d_out;

    const int N = in_sizes[0] / 6;
    const int E = in_sizes[2] / 2;
    const int G = in_sizes[5] / 6;

    const int* srcArr = edge_index;
    const int* dstArr = edge_index + E;

    // workspace layout
    char* wsb = (char*)d_ws;
    size_t off = 0;
    float* xl      = (float*)(wsb + off); off += (size_t)N * 256 * 4;
    float* xr      = (float*)(wsb + off); off += (size_t)N * 256 * 4;
    int2*  csr     = (int2*) (wsb + off); off += (size_t)E * 8;
    int*   row_ptr = (int*)  (wsb + off); off += (size_t)(N + 1) * 4;
    int*   cursor  = (int*)  (wsb + off); off += (size_t)N * 4;
    int*   bsum    = (int*)  (wsb + off); off += 64 * 4;
    size_t zs = off;  // ---- zeroed region ----
    int*   degi    = (int*)  (wsb + off); off += (size_t)N * 4;
    float* pooled  = (float*)(wsb + off); off += (size_t)G * 64 * 4;
    float* gcnt    = (float*)(wsb + off); off += (size_t)G * 4;
    size_t ze = off;
    (void)ws_size; (void)n_in; (void)out_size;

    hipMemsetAsync(wsb + zs, 0, ze - zs, stream);

    const int nb1 = (N + 1023) / 1024;  // <= 64 for N <= 65536
    k_deg<<<(E + 255) / 256, 256, 0, stream>>>(dstArr, degi, E);
    k_enc_xlxr<<<(N + 15) / 16, 256, 0, stream>>>(x, node_type, type_emb, enc_W, enc_b,
                                                  Wl, bl, Wr, br, xl, xr, N);
    k_scan1<<<nb1, 1024, 0, stream>>>(degi, row_ptr, bsum, N);
    k_scan2<<<1, 64, 0, stream>>>(bsum, row_ptr, nb1, N);
    k_scan3<<<nb1, 1024, 0, stream>>>(row_ptr, cursor, bsum, N);
    k_fill<<<(E + 255) / 256, 256, 0, stream>>>(srcArr, dstArr, cursor, csr, E);
    k_gather<<<(N + 3) / 4, 256, 0, stream>>>(csr, edge_attr, row_ptr, We, att, xl, xr,
                                              conv_bias, batch, pooled, gcnt, N);
    k_final<<<G, 128, 0, stream>>>(pooled, gcnt, gf, gW, gb, h1W, h1b, h2W, h2b, out, G);
}

// Round 9
// 748.200 us; speedup vs baseline: 3.1602x; 1.0447x over previous
//
#include <hip/hip_runtime.h>

#define NEG_SLOPE 0.2f

template <int CTRL>
__device__ __forceinline__ float dppadd(float x) {
    int y = __builtin_amdgcn_update_dpp(0, __float_as_int(x), CTRL, 0xf, 0xf, true);
    return x + __int_as_float(y);
}

// ---------------- K1: degree histogram ----------------
__global__ void k_deg(const int* __restrict__ dst, int* __restrict__ degi, int E) {
    int e = blockIdx.x * blockDim.x + threadIdx.x;
    if (e >= E) return;
    atomicAdd(&degi[dst[e]], 1);
}

// ---------------- K2a: per-block scan (1024 elems/block) ----------------
__global__ void __launch_bounds__(1024) k_scan1(const int* __restrict__ degi,
                                                int* __restrict__ row_ptr,
                                                int* __restrict__ bsum, int N) {
    __shared__ int wsum[16];
    int tid = threadIdx.x, lane = tid & 63, wid = tid >> 6;
    int i = blockIdx.x * 1024 + tid;
    int v = (i < N) ? degi[i] : 0;
    int x = v;
#pragma unroll
    for (int off = 1; off < 64; off <<= 1) {
        int y = __shfl_up(x, off, 64);
        if (lane >= off) x += y;
    }
    if (lane == 63) wsum[wid] = x;
    __syncthreads();
    if (wid == 0) {
        int w = (lane < 16) ? wsum[lane] : 0;
#pragma unroll
        for (int off = 1; off < 16; off <<= 1) {
            int y = __shfl_up(w, off, 64);
            if (lane >= off) w += y;
        }
        if (lane < 16) wsum[lane] = w;
    }
    __syncthreads();
    int wofs = (wid > 0) ? wsum[wid - 1] : 0;
    if (i < N) row_ptr[i] = wofs + x - v;  // block-local exclusive
    if (tid == 0) bsum[blockIdx.x] = wsum[15];
}

// ---------------- K2b: scan of block sums (<=64 blocks) ----------------
__global__ void k_scan2(int* __restrict__ bsum, int* __restrict__ row_ptr, int nb, int N) {
    int lane = threadIdx.x & 63;
    int v = (lane < nb) ? bsum[lane] : 0;
    int x = v;
#pragma unroll
    for (int off = 1; off < 64; off <<= 1) {
        int y = __shfl_up(x, off, 64);
        if (lane >= off) x += y;
    }
    if (lane < nb) bsum[lane] = x - v;  // exclusive
    if (lane == 63) row_ptr[N] = x;     // grand total
}

// ---------------- K2c: apply block offsets ----------------
__global__ void __launch_bounds__(1024) k_scan3(int* __restrict__ row_ptr,
                                                int* __restrict__ cursor,
                                                const int* __restrict__ bsum, int N) {
    int i = blockIdx.x * 1024 + threadIdx.x;
    if (i < N) {
        int r = row_ptr[i] + bsum[blockIdx.x];
        row_ptr[i] = r;
        cursor[i] = r;
    }
}

// ---------------- K3: CSR fill with (src, edge_id) pairs ----------------
__global__ void k_fill(const int* __restrict__ src, const int* __restrict__ dst,
                       int* __restrict__ cursor, int2* __restrict__ csr, int E) {
    int e = blockIdx.x * blockDim.x + threadIdx.x;
    if (e >= E) return;
    int d = dst[e];
    int pos = atomicAdd(&cursor[d], 1);
    csr[pos] = make_int2(src[e], e);
}

// ---------------- K4: fused node encoder + xl/xr transforms ----------------
__global__ void __launch_bounds__(256) k_enc_xlxr(
    const float* __restrict__ x, const int* __restrict__ node_type,
    const float* __restrict__ type_emb,
    const float* __restrict__ enc_W, const float* __restrict__ enc_b,
    const float* __restrict__ Wl, const float* __restrict__ bl,
    const float* __restrict__ Wr, const float* __restrict__ br,
    float* __restrict__ xl, float* __restrict__ xr, int N) {
    const int NPB = 16;
    __shared__ float sIn[NPB][10];
    __shared__ float sH[NPB][64];
    int tid = threadIdx.x;
    int v0 = blockIdx.x * NPB;
    for (int i = tid; i < NPB * 10; i += 256) {
        int v = i / 10, k = i % 10;
        int vg = v0 + v;
        float val = 0.f;
        if (vg < N) {
            if (k < 6) val = x[(size_t)vg * 6 + k];
            else       val = type_emb[node_type[vg] * 4 + (k - 6)];
        }
        sIn[v][k] = val;
    }
    __syncthreads();
    for (int i = tid; i < NPB * 64; i += 256) {
        int v = i >> 6, j = i & 63;
        float acc = enc_b[j];
#pragma unroll
        for (int k = 0; k < 10; ++k) acc += sIn[v][k] * enc_W[k * 64 + j];
        sH[v][j] = fmaxf(acc, 0.f);
    }
    __syncthreads();
    int j = tid;
    float accL[NPB], accR[NPB];
    float blj = bl[j], brj = br[j];
#pragma unroll
    for (int v = 0; v < NPB; ++v) { accL[v] = blj; accR[v] = brj; }
    for (int k = 0; k < 64; ++k) {
        float wl = Wl[k * 256 + j], wr = Wr[k * 256 + j];
#pragma unroll
        for (int v = 0; v < NPB; ++v) {
            float hv = sH[v][k];
            accL[v] += hv * wl;
            accR[v] += hv * wr;
        }
    }
#pragma unroll
    for (int v = 0; v < NPB; ++v) {
        int vg = v0 + v;
        if (vg < N) {
            xl[(size_t)vg * 256 + j] = accL[v];
            xr[(size_t)vg * 256 + j] = accR[v];
        }
    }
}

// ---------------- K5: fused per-(node,head) GATv2 ----------------
// block = one node; wave w = head w; lane = col within head.
__global__ void __launch_bounds__(256, 6) k_gather(
    const int2* __restrict__ csr, const float* __restrict__ edge_attr,
    const int* __restrict__ row_ptr, const float* __restrict__ We,
    const float* __restrict__ att, const float* __restrict__ xl,
    const float* __restrict__ xr, const float* __restrict__ conv_bias,
    const int* __restrict__ batch, float* __restrict__ pooled,
    float* __restrict__ gcnt, int N) {
    __shared__ float sO[4][64];
    int tid = threadIdx.x;
    int lane = tid & 63;
    int h = tid >> 6;
    int v = blockIdx.x;
    int col = h * 64 + lane;

    // per-lane weight slice: 11 VGPRs
    float rWe[11];
#pragma unroll
    for (int k = 0; k < 11; ++k) rWe[k] = We[k * 256 + col];
    float attC = att[col];
    float xrC = xr[(size_t)v * 256 + col];

    float acc = 0.f, den = 0.f, eaC = 0.f;

    int rs = row_ptr[v], re = row_ptr[v + 1];
    int deg = re - rs;

    auto REDUCE = [&](float t2) -> float {
        t2 = dppadd<0xB1>(t2);   // quad_perm [1,0,3,2]  (xor 1)
        t2 = dppadd<0x4E>(t2);   // quad_perm [2,3,0,1]  (xor 2)
        t2 = dppadd<0x141>(t2);  // row_half_mirror (sum of 8)
        t2 = dppadd<0x140>(t2);  // row_mirror (sum of 16)
        t2 += __shfl_xor(t2, 16, 64);
        t2 += __shfl_xor(t2, 32, 64);
        return t2;
    };

    auto PROC = [&](const float (&a)[11], float xv) {
        float ee = 0.f;
#pragma unroll
        for (int k = 0; k < 11; ++k) ee += a[k] * rWe[k];
        eaC += ee;
        float m = xv + xrC + ee;
        m = (m > 0.f) ? m : NEG_SLOPE * m;
        float t2 = REDUCE(m * attC);
        float p = __expf(t2);
        acc += p * xv;
        den += p;
    };

    for (int base = rs; base < re; base += 64) {
        int cnt = re - base; if (cnt > 64) cnt = 64;
        int2 se = csr[base + ((lane < cnt) ? lane : cnt - 1)];
        int myS = se.x, myE = se.y;

        auto LOADE = [&](int t, float (&a)[11], float& xv) {
            int s = __builtin_amdgcn_readlane(myS, t);
            int e = __builtin_amdgcn_readlane(myE, t);
            const float* ap = edge_attr + (size_t)e * 11;
#pragma unroll
            for (int k = 0; k < 11; ++k) a[k] = ap[k];
            xv = xl[(size_t)s * 256 + col];
        };

        float aA[11], aB[11];
        float xA, xB;
        LOADE(0, aA, xA);
        int t = 0;
        while (true) {
            if (t + 1 < cnt) LOADE(t + 1, aB, xB);
            PROC(aA, xA);
            ++t; if (t >= cnt) break;
            if (t + 1 < cnt) LOADE(t + 1, aA, xA);
            PROC(aB, xB);
            ++t; if (t >= cnt) break;
        }
    }

    // self-loop: attrs = mean of incoming edge attrs; ee linear -> eaC/deg
    {
        float inv = 1.f / fmaxf((float)deg, 1.f);
        float xs = xl[(size_t)v * 256 + col];
        float ee = eaC * inv;
        float m = xs + xrC + ee;
        m = (m > 0.f) ? m : NEG_SLOPE * m;
        float t2 = REDUCE(m * attC);
        float p = __expf(t2);
        acc += p * xs;
        den += p;
    }

    sO[h][lane] = acc / (den + 1e-16f);
    __syncthreads();
    if (tid < 64) {
        float s4 = sO[0][lane] + sO[1][lane] + sO[2][lane] + sO[3][lane];
        float hc = fmaxf(0.25f * s4 + conv_bias[lane], 0.f);
        int g = batch[v];
        atomicAdd(&pooled[g * 64 + lane], hc);
        if (lane == 0) atomicAdd(&gcnt[g], 1.0f);
    }
}

// ---------------- K6: per-graph MLP head ----------------
__global__ void k_final(const float* __restrict__ pooled, const float* __restrict__ gcnt,
                        const float* __restrict__ gf, const float* __restrict__ gW,
                        const float* __restrict__ gb, const float* __restrict__ h1W,
                        const float* __restrict__ h1b, const float* __restrict__ h2W,
                        const float* __restrict__ h2b, float* __restrict__ out, int G) {
    __shared__ float sComb[128];
    __shared__ float sHid[64];
    int g = blockIdx.x;
    int t = threadIdx.x;
    if (t < 64) {
        sComb[t] = pooled[(size_t)g * 64 + t] / fmaxf(gcnt[g], 1.0f);
    } else {
        int j = t - 64;
        float acc = gb[j];
#pragma unroll
        for (int k = 0; k < 6; ++k) acc += gf[(size_t)g * 6 + k] * gW[k * 64 + j];
        sComb[64 + j] = fmaxf(acc, 0.f);
    }
    __syncthreads();
    if (t < 64) {
        float acc = h1b[t];
#pragma unroll
        for (int k = 0; k < 128; ++k) acc += sComb[k] * h1W[k * 64 + t];
        sHid[t] = fmaxf(acc, 0.f);
    }
    __syncthreads();
    if (t < 64) {
        float p = sHid[t] * h2W[t];
#pragma unroll
        for (int off = 32; off > 0; off >>= 1) p += __shfl_xor(p, off, 64);
        if (t == 0) out[g] = p + h2b[0];
    }
}

extern "C" void kernel_launch(void* const* d_in, const int* in_sizes, int n_in,
                              void* d_out, int out_size, void* d_ws, size_t ws_size,
                              hipStream_t stream) {
    const float* x         = (const float*)d_in[0];
    const int*   node_type = (const int*)d_in[1];
    const int*   edge_index= (const int*)d_in[2];
    const float* edge_attr = (const float*)d_in[3];
    const int*   batch     = (const int*)d_in[4];
    const float* gf        = (const float*)d_in[5];
    const float* type_emb  = (const float*)d_in[6];
    const float* enc_W     = (const float*)d_in[7];
    const float* enc_b     = (const float*)d_in[8];
    const float* Wl        = (const float*)d_in[9];
    const float* bl        = (const float*)d_in[10];
    const float* Wr        = (const float*)d_in[11];
    const float* br        = (const float*)d_in[12];
    const float* We        = (const float*)d_in[13];
    const float* att       = (const float*)d_in[14];
    const float* conv_bias = (const float*)d_in[15];
    const float* gW        = (const float*)d_in[16];
    const float* gb        = (const float*)d_in[17];
    const float* h1W       = (const float*)d_in[18];
    const float* h1b       = (const float*)d_in[19];
    const float* h2W       = (const float*)d_in[20];
    const float* h2b       = (const float*)d_in[21];
    float* out = (float*)d_out;

    const int N = in_sizes[0] / 6;
    const int E = in_sizes[2] / 2;
    const int G = in_sizes[5] / 6;

    const int* srcArr = edge_index;
    const int* dstArr = edge_index + E;

    // workspace layout
    char* wsb = (char*)d_ws;
    size_t off = 0;
    float* xl      = (float*)(wsb + off); off += (size_t)N * 256 * 4;
    float* xr      = (float*)(wsb + off); off += (size_t)N * 256 * 4;
    int2*  csr     = (int2*) (wsb + off); off += (size_t)E * 8;
    int*   row_ptr = (int*)  (wsb + off); off += (size_t)(N + 1) * 4;
    int*   cursor  = (int*)  (wsb + off); off += (size_t)N * 4;
    int*   bsum    = (int*)  (wsb + off); off += 64 * 4;
    size_t zs = off;  // ---- zeroed region ----
    int*   degi    = (int*)  (wsb + off); off += (size_t)N * 4;
    float* pooled  = (float*)(wsb + off); off += (size_t)G * 64 * 4;
    float* gcnt    = (float*)(wsb + off); off += (size_t)G * 4;
    size_t ze = off;
    (void)ws_size; (void)n_in; (void)out_size;

    (void)hipMemsetAsync(wsb + zs, 0, ze - zs, stream);

    const int nb1 = (N + 1023) / 1024;  // <= 64 for N <= 65536
    k_deg<<<(E + 255) / 256, 256, 0, stream>>>(dstArr, degi, E);
    k_enc_xlxr<<<(N + 15) / 16, 256, 0, stream>>>(x, node_type, type_emb, enc_W, enc_b,
                                                  Wl, bl, Wr, br, xl, xr, N);
    k_scan1<<<nb1, 1024, 0, stream>>>(degi, row_ptr, bsum, N);
    k_scan2<<<1, 64, 0, stream>>>(bsum, row_ptr, nb1, N);
    k_scan3<<<nb1, 1024, 0, stream>>>(row_ptr, cursor, bsum, N);
    k_fill<<<(E + 255) / 256, 256, 0, stream>>>(srcArr, dstArr, cursor, csr, E);
    k_gather<<<N, 256, 0, stream>>>(csr, edge_attr, row_ptr, We, att, xl, xr,
                                    conv_bias, batch, pooled, gcnt, N);
    k_final<<<G, 128, 0, stream>>>(pooled, gcnt, gf, gW, gb, h1W, h1b, h2W, h2b, out, G);
}